// Round 14
// baseline (71.116 us; speedup 1.0000x reference)
//
#include <hip/hip_runtime.h>

typedef unsigned int uint;
typedef _Float16 half2v __attribute__((ext_vector_type(2)));
typedef _Float16 half8  __attribute__((ext_vector_type(8)));
typedef float    f32x4  __attribute__((ext_vector_type(4)));

#define BATCH   8192
#define DIM     128
#define NCLS    512
#define TMARGIN 0.3f
#define BIGF    3.402823466e+38f
#define MAXM    128
#define SEGS    16
#define TPB     4      // j-tiles per block (512 cols per segment)
#define NPH     (TPB * 4)

// ---------- k_prep: norms + f16 (hi-only) cast -------------------------------
__global__ __launch_bounds__(256) void k_prep(
    const float* __restrict__ emb, _Float16* __restrict__ eh,
    float* __restrict__ norms) {
  int w = threadIdx.x >> 6, lane = threadIdx.x & 63;
  int row = blockIdx.x * 4 + w;
  float2 v = reinterpret_cast<const float2*>(emb + (size_t)row * DIM)[lane];
  half2v hv = {(_Float16)v.x, (_Float16)v.y};
  reinterpret_cast<half2v*>(eh + (size_t)row * DIM)[lane] = hv;
  float s = v.x * v.x + v.y * v.y;
  #pragma unroll
  for (int off = 32; off; off >>= 1) s += __shfl_xor(s, off);
  if (lane == 0) norms[row] = s;
}

// ---------- k_hp: hardest positive per class (self-gathered member list) -----
__global__ __launch_bounds__(256) void k_hp(
    const float* __restrict__ emb, const int* __restrict__ labels,
    const float* __restrict__ norms, float* __restrict__ hp) {
  __shared__ int mem[MAXM];
  __shared__ float nrm[MAXM];
  __shared__ int cnt;
  int c = blockIdx.x;
  if (threadIdx.x == 0) cnt = 0;
  __syncthreads();
  for (int i = threadIdx.x; i < BATCH; i += 256)
    if (labels[i] == c) {
      int p = atomicAdd(&cnt, 1);
      if (p < MAXM) mem[p] = i;
    }
  __syncthreads();
  int m = cnt < MAXM ? cnt : MAXM;
  if (threadIdx.x < m) nrm[threadIdx.x] = norms[mem[threadIdx.x]];
  __syncthreads();
  int w = threadIdx.x >> 6, lane = threadIdx.x & 63;
  int g = lane >> 4, gl = lane & 15;
  for (int a = w; a < m; a += 4) {
    int i = mem[a];
    const float4* pi = reinterpret_cast<const float4*>(emb + (size_t)i * DIM + gl * 8);
    float4 xi0 = pi[0], xi1 = pi[1];
    float ni = nrm[a];
    float best = 0.f;
    for (int b = g; b < m; b += 4) {
      if (b == a) continue;
      int j = mem[b];
      const float4* pj = reinterpret_cast<const float4*>(emb + (size_t)j * DIM + gl * 8);
      float4 xj0 = pj[0], xj1 = pj[1];
      float d = xi0.x*xj0.x + xi0.y*xj0.y + xi0.z*xj0.z + xi0.w*xj0.w
              + xi1.x*xj1.x + xi1.y*xj1.y + xi1.z*xj1.z + xi1.w*xj1.w;
      #pragma unroll
      for (int off = 1; off < 16; off <<= 1) d += __shfl_xor(d, off);
      float sq = fmaxf(ni + nrm[b] - 2.f * d, 0.f);
      best = fmaxf(best, sq);
    }
    best = fmaxf(best, __shfl_xor(best, 16));
    best = fmaxf(best, __shfl_xor(best, 32));
    if (lane == 0) hp[i] = best > 0.f ? sqrtf(best) : 0.f;
  }
}

// ---------- k_main: hh-only full sweep, 16-phase counted-vmcnt, 4x8KB bufs ---
// block = (panel 128 rows, seg 512 cols). 4 tiles x 4 K-quarters = 16 phases.
// Grid 1024 = 4 blocks/CU (LDS 36KB). Stage 2 ahead into buf (p+2)&3, read
// buf p&3, ONE barrier per phase. vmcnt(4) steady; drain 2/0 at NPH-2/NPH-1.
__global__ __launch_bounds__(256, 2) void k_main(
    const _Float16* __restrict__ eh, const int* __restrict__ labels,
    const float* __restrict__ norms, const float* __restrict__ hp,
    float* __restrict__ rowres) {
  __shared__ __align__(16) char lds[36864];   // 4x8KB bufs + 2KB norms + 2KB labels
  const int t = threadIdx.x, lane = t & 63, w = t >> 6;
  const int r16 = lane & 15, kg = lane >> 4;
  const int panel = blockIdx.x >> 4, seg = blockIdx.x & 15;
  const int i0 = panel * 128, jseg = seg * (TPB * 128);
  float* snorm = reinterpret_cast<float*>(lds + 32768);
  int*   slab  = reinterpret_cast<int*>(lds + 34816);

  // B-frag read byte offsets within a buffer (64B row stride, k-slot XOR swz)
  int boff[8];
  #pragma unroll
  for (int n = 0; n < 8; ++n) {
    int col = 16 * n + r16;
    boff[n] = col * 64 + ((kg ^ ((col >> 1) & 3)) << 4);
  }

  // staging bases: 2 x 16B units per thread per phase (8KB buffer)
  const _Float16* gbase[2];
  int lbase[2];
  #pragma unroll
  for (int it = 0; it < 2; ++it) {
    int u = it * 256 + t;                 // unit 0..511
    int col = u >> 2, s = u & 3;
    int kgs = s ^ ((col >> 1) & 3);       // pre-swizzled global k-slot
    gbase[it] = eh + (size_t)col * DIM + kgs * 8;
    lbase[it] = it * 4096 + w * 1024;     // linear LDS dest (lane*16 added by HW)
  }
  auto stage = [&](int jt, int kq, int buf) {
    size_t off = (size_t)(jseg + jt * 128) * DIM + kq * 32;
    #pragma unroll
    for (int it = 0; it < 2; ++it) {
      __builtin_amdgcn_global_load_lds(
          (const __attribute__((address_space(1))) void*)(gbase[it] + off),
          (__attribute__((address_space(3))) void*)(lds + buf * 8192 + lbase[it]),
          16, 0, 0);
    }
  };

  // segment norms/labels (512 each) -> LDS via waves 0,1; then first 2 stages
  if (t < 128) {
    __builtin_amdgcn_global_load_lds(
        (const __attribute__((address_space(1))) void*)(norms + jseg + t * 4),
        (__attribute__((address_space(3))) void*)(lds + 32768 + w * 1024), 16, 0, 0);
    __builtin_amdgcn_global_load_lds(
        (const __attribute__((address_space(1))) void*)(labels + jseg + t * 4),
        (__attribute__((address_space(3))) void*)(lds + 34816 + w * 1024), 16, 0, 0);
  }
  stage(0, 0, 0);
  stage(0, 1, 1);

  // A fragments (hi only): rows i0 + 32w + 16m + r16, full K in quarters
  half8 ah[2][4];
  #pragma unroll
  for (int m = 0; m < 2; ++m) {
    size_t rbase = (size_t)(i0 + 32 * w + 16 * m + r16) * DIM + kg * 8;
    #pragma unroll
    for (int ks = 0; ks < 4; ++ks)
      ah[m][ks] = *reinterpret_cast<const half8*>(eh + rbase + ks * 32);
  }

  // row constants + running maxes (t-space: t = 2*dot - nj, dist^2 = ni - t)
  float c2[2][4], rmax[2][4], smax[2][4];
  int li[2][4];
  #pragma unroll
  for (int m = 0; m < 2; ++m)
    #pragma unroll
    for (int q = 0; q < 4; ++q) {
      int gi = i0 + 32 * w + 16 * m + 4 * kg + q;
      float nv = norms[gi], h = hp[gi];
      c2[m][q] = nv - h * h;
      li[m][q] = labels[gi];
      rmax[m][q] = -BIGF;
      smax[m][q] = -BIGF;
    }

  f32x4 acc[2][8];
  #pragma unroll
  for (int m = 0; m < 2; ++m)
    #pragma unroll
    for (int n = 0; n < 8; ++n) acc[m][n] = (f32x4){0.f, 0.f, 0.f, 0.f};

  int p = 0;
  for (int jt = 0; jt < TPB; ++jt) {
    #pragma unroll
    for (int kq = 0; kq < 4; ++kq) {
      int np2 = p + 2;
      if (np2 < NPH) stage(np2 >> 2, np2 & 3, np2 & 3);
      if (p < NPH - 2)       asm volatile("s_waitcnt vmcnt(4)" ::: "memory");
      else if (p == NPH - 2) asm volatile("s_waitcnt vmcnt(2)" ::: "memory");
      else                   asm volatile("s_waitcnt vmcnt(0)" ::: "memory");
      __builtin_amdgcn_s_barrier();
      __builtin_amdgcn_sched_barrier(0);
      const char* pb = lds + (p & 3) * 8192;
      __builtin_amdgcn_s_setprio(1);
      #pragma unroll
      for (int n = 0; n < 8; ++n) {
        half8 bh = *reinterpret_cast<const half8*>(pb + boff[n]);
        #pragma unroll
        for (int m = 0; m < 2; ++m)
          acc[m][n] = __builtin_amdgcn_mfma_f32_16x16x32_f16(ah[m][kq], bh, acc[m][n], 0, 0, 0);
      }
      __builtin_amdgcn_s_setprio(0);
      if (kq == 3) {
        // tile epilogue (register-only, t-space); col consts read from LDS
        #pragma unroll
        for (int n = 0; n < 8; ++n) {
          float njv = snorm[jt * 128 + 16 * n + r16];
          int   ljv = slab[jt * 128 + 16 * n + r16];
          #pragma unroll
          for (int m = 0; m < 2; ++m)
            #pragma unroll
            for (int q = 0; q < 4; ++q) {
              float tv = fmaf(2.f, acc[m][n][q], -njv);
              float tm = (li[m][q] != ljv) ? tv : -BIGF;
              rmax[m][q] = fmaxf(rmax[m][q], tm);
              float tl = (tm < c2[m][q]) ? tm : -BIGF;
              smax[m][q] = fmaxf(smax[m][q], tl);
              acc[m][n][q] = 0.f;
            }
        }
      }
      ++p;
    }
  }

  // block end: reduce over the 16 col-lanes, write per-segment row results
  float2* pp = reinterpret_cast<float2*>(rowres);
  #pragma unroll
  for (int m = 0; m < 2; ++m)
    #pragma unroll
    for (int q = 0; q < 4; ++q) {
      float r = rmax[m][q], s = smax[m][q];
      #pragma unroll
      for (int off = 1; off < 16; off <<= 1) {
        r = fmaxf(r, __shfl_xor(r, off));
        s = fmaxf(s, __shfl_xor(s, off));
      }
      if (r16 == 0) {
        int gi = i0 + 32 * w + 16 * m + 4 * kg + q;
        pp[(size_t)gi * SEGS + seg] = make_float2(r, s);
      }
    }
}

// ---------- k_red: per-row combine (1 thread/row, 32 blocks) -----------------
__global__ __launch_bounds__(256) void k_red(
    const float* __restrict__ norms, const float* __restrict__ hp,
    const float* __restrict__ rowres, float* __restrict__ partial) {
  int row = blockIdx.x * 256 + threadIdx.x;
  const float2* pp = reinterpret_cast<const float2*>(rowres) + (size_t)row * SEGS;
  float rmax = -BIGF, smax = -BIGF;
  #pragma unroll
  for (int s = 0; s < SEGS; ++s) {
    float2 v = pp[s];
    rmax = fmaxf(rmax, v.x);
    smax = fmaxf(smax, v.y);
  }
  float ni = norms[row], h = hp[row];
  float c1 = ni - (h + TMARGIN) * (h + TMARGIN);
  bool has_neg = rmax > -1e37f;
  float neg_sq  = fmaxf(ni - rmax, 0.f);
  float semi_sq = (smax > c1) ? fmaxf(ni - smax, 0.f) : neg_sq;
  float total = 0.f, count = 0.f;
  if (h > 0.f && has_neg) {
    total = fmaxf(h - sqrtf(semi_sq) + TMARGIN, 0.f);
    count = 1.f;
  }
  #pragma unroll
  for (int off = 32; off; off >>= 1) {
    total += __shfl_xor(total, off);
    count += __shfl_xor(count, off);
  }
  __shared__ float st[4], sc[4];
  int w = threadIdx.x >> 6, lane = threadIdx.x & 63;
  if (lane == 0) { st[w] = total; sc[w] = count; }
  __syncthreads();
  if (threadIdx.x == 0) {
    float2* po = reinterpret_cast<float2*>(partial);
    po[blockIdx.x] = make_float2(st[0] + st[1] + st[2] + st[3],
                                 sc[0] + sc[1] + sc[2] + sc[3]);
  }
}

// ---------- k_out: final scalar ----------------------------------------------
__global__ void k_out(const float* __restrict__ partial, float* __restrict__ out) {
  const float2* pp = reinterpret_cast<const float2*>(partial);
  int lane = threadIdx.x;
  float T = 0.f, C = 0.f;
  if (lane < 32) { float2 a = pp[lane]; T = a.x; C = a.y; }
  #pragma unroll
  for (int off = 32; off; off >>= 1) {
    T += __shfl_xor(T, off);
    C += __shfl_xor(C, off);
  }
  if (lane == 0) out[0] = C > 0.f ? T / C : 0.f;
}

extern "C" void kernel_launch(void* const* d_in, const int* in_sizes, int n_in,
                              void* d_out, int out_size, void* d_ws, size_t ws_size,
                              hipStream_t stream) {
  const float* emb  = (const float*)d_in[0];
  const int* labels = (const int*)d_in[1];
  float* out        = (float*)d_out;

  _Float16* eh  = (_Float16*)d_ws;                     // 2 MB
  float* norms  = (float*)(eh + (size_t)BATCH * DIM);  // 32 KB
  float* hp     = norms + BATCH;                       // 32 KB
  float* rowres = hp + BATCH;                          // 1 MB (8192 x 16 float2)
  float* partial = rowres + (size_t)BATCH * SEGS * 2;  // 256 B

  k_prep<<<BATCH / 4, 256, 0, stream>>>(emb, eh, norms);
  k_hp<<<NCLS, 256, 0, stream>>>(emb, labels, norms, hp);
  k_main<<<(BATCH / 128) * SEGS, 256, 0, stream>>>(eh, labels, norms, hp, rowres);
  k_red<<<BATCH / 256, 256, 0, stream>>>(norms, hp, rowres, partial);
  k_out<<<1, 64, 0, stream>>>(partial, out);
}

// Round 15
// 69.095 us; speedup vs baseline: 1.0292x; 1.0292x over previous
//
#include <hip/hip_runtime.h>

typedef unsigned int uint;
typedef _Float16 half2v __attribute__((ext_vector_type(2)));
typedef _Float16 half8  __attribute__((ext_vector_type(8)));
typedef float    f32x4  __attribute__((ext_vector_type(4)));

#define BATCH   8192
#define DIM     128
#define NCLS    512
#define TMARGIN 0.3f
#define BIGF    3.402823466e+38f
#define MAXM    128
#define SEGS    16
#define TPB     4      // j-tiles per block (512 cols per segment)
#define NPH     (TPB * 4)

// ---------- k_preh: fused prep (blocks 0..2047) + hardest-positive (2048..2559)
// hp blocks are prep-independent (member norms computed from emb directly),
// so both halves overlap inside one dispatch.
__global__ __launch_bounds__(256) void k_preh(
    const float* __restrict__ emb, const int* __restrict__ labels,
    _Float16* __restrict__ eh, float* __restrict__ norms,
    float* __restrict__ hp, uint* __restrict__ counter) {
  if (blockIdx.x < 2048) {
    if (blockIdx.x == 0 && threadIdx.x == 0) *counter = 0;  // finalize counter
    int w = threadIdx.x >> 6, lane = threadIdx.x & 63;
    int row = blockIdx.x * 4 + w;
    float2 v = reinterpret_cast<const float2*>(emb + (size_t)row * DIM)[lane];
    half2v hv = {(_Float16)v.x, (_Float16)v.y};
    reinterpret_cast<half2v*>(eh + (size_t)row * DIM)[lane] = hv;
    float s = v.x * v.x + v.y * v.y;
    #pragma unroll
    for (int off = 32; off; off >>= 1) s += __shfl_xor(s, off);
    if (lane == 0) norms[row] = s;
    return;
  }
  // ---- hardest positive for class c (self-contained) ----
  __shared__ int mem[MAXM];
  __shared__ float nrm[MAXM];
  __shared__ int cnt;
  int c = blockIdx.x - 2048;
  if (threadIdx.x == 0) cnt = 0;
  __syncthreads();
  for (int i = threadIdx.x; i < BATCH; i += 256)
    if (labels[i] == c) {
      int p = atomicAdd(&cnt, 1);
      if (p < MAXM) mem[p] = i;
    }
  __syncthreads();
  int m = cnt < MAXM ? cnt : MAXM;
  if (threadIdx.x < m) {
    const float4* pe = reinterpret_cast<const float4*>(
        emb + (size_t)mem[threadIdx.x] * DIM);
    float s = 0.f;
    #pragma unroll
    for (int k = 0; k < 32; ++k) {
      float4 x = pe[k];
      s += x.x * x.x + x.y * x.y + x.z * x.z + x.w * x.w;
    }
    nrm[threadIdx.x] = s;
  }
  __syncthreads();
  int w = threadIdx.x >> 6, lane = threadIdx.x & 63;
  int g = lane >> 4, gl = lane & 15;
  for (int a = w; a < m; a += 4) {
    int i = mem[a];
    const float4* pi = reinterpret_cast<const float4*>(emb + (size_t)i * DIM + gl * 8);
    float4 xi0 = pi[0], xi1 = pi[1];
    float ni = nrm[a];
    float best = 0.f;
    for (int b = g; b < m; b += 4) {
      if (b == a) continue;
      int j = mem[b];
      const float4* pj = reinterpret_cast<const float4*>(emb + (size_t)j * DIM + gl * 8);
      float4 xj0 = pj[0], xj1 = pj[1];
      float d = xi0.x*xj0.x + xi0.y*xj0.y + xi0.z*xj0.z + xi0.w*xj0.w
              + xi1.x*xj1.x + xi1.y*xj1.y + xi1.z*xj1.z + xi1.w*xj1.w;
      #pragma unroll
      for (int off = 1; off < 16; off <<= 1) d += __shfl_xor(d, off);
      float sq = fmaxf(ni + nrm[b] - 2.f * d, 0.f);
      best = fmaxf(best, sq);
    }
    best = fmaxf(best, __shfl_xor(best, 16));
    best = fmaxf(best, __shfl_xor(best, 32));
    if (lane == 0) hp[i] = best > 0.f ? sqrtf(best) : 0.f;
  }
}

// ---------- k_main: hh-only full sweep, 16-phase counted-vmcnt, 4x8KB bufs ---
// Byte-identical to the round-14 passing kernel.
__global__ __launch_bounds__(256, 2) void k_main(
    const _Float16* __restrict__ eh, const int* __restrict__ labels,
    const float* __restrict__ norms, const float* __restrict__ hp,
    float* __restrict__ rowres) {
  __shared__ __align__(16) char lds[36864];   // 4x8KB bufs + 2KB norms + 2KB labels
  const int t = threadIdx.x, lane = t & 63, w = t >> 6;
  const int r16 = lane & 15, kg = lane >> 4;
  const int panel = blockIdx.x >> 4, seg = blockIdx.x & 15;
  const int i0 = panel * 128, jseg = seg * (TPB * 128);
  float* snorm = reinterpret_cast<float*>(lds + 32768);
  int*   slab  = reinterpret_cast<int*>(lds + 34816);

  int boff[8];
  #pragma unroll
  for (int n = 0; n < 8; ++n) {
    int col = 16 * n + r16;
    boff[n] = col * 64 + ((kg ^ ((col >> 1) & 3)) << 4);
  }

  const _Float16* gbase[2];
  int lbase[2];
  #pragma unroll
  for (int it = 0; it < 2; ++it) {
    int u = it * 256 + t;
    int col = u >> 2, s = u & 3;
    int kgs = s ^ ((col >> 1) & 3);
    gbase[it] = eh + (size_t)col * DIM + kgs * 8;
    lbase[it] = it * 4096 + w * 1024;
  }
  auto stage = [&](int jt, int kq, int buf) {
    size_t off = (size_t)(jseg + jt * 128) * DIM + kq * 32;
    #pragma unroll
    for (int it = 0; it < 2; ++it) {
      __builtin_amdgcn_global_load_lds(
          (const __attribute__((address_space(1))) void*)(gbase[it] + off),
          (__attribute__((address_space(3))) void*)(lds + buf * 8192 + lbase[it]),
          16, 0, 0);
    }
  };

  if (t < 128) {
    __builtin_amdgcn_global_load_lds(
        (const __attribute__((address_space(1))) void*)(norms + jseg + t * 4),
        (__attribute__((address_space(3))) void*)(lds + 32768 + w * 1024), 16, 0, 0);
    __builtin_amdgcn_global_load_lds(
        (const __attribute__((address_space(1))) void*)(labels + jseg + t * 4),
        (__attribute__((address_space(3))) void*)(lds + 34816 + w * 1024), 16, 0, 0);
  }
  stage(0, 0, 0);
  stage(0, 1, 1);

  half8 ah[2][4];
  #pragma unroll
  for (int m = 0; m < 2; ++m) {
    size_t rbase = (size_t)(i0 + 32 * w + 16 * m + r16) * DIM + kg * 8;
    #pragma unroll
    for (int ks = 0; ks < 4; ++ks)
      ah[m][ks] = *reinterpret_cast<const half8*>(eh + rbase + ks * 32);
  }

  float c2[2][4], rmax[2][4], smax[2][4];
  int li[2][4];
  #pragma unroll
  for (int m = 0; m < 2; ++m)
    #pragma unroll
    for (int q = 0; q < 4; ++q) {
      int gi = i0 + 32 * w + 16 * m + 4 * kg + q;
      float nv = norms[gi], h = hp[gi];
      c2[m][q] = nv - h * h;
      li[m][q] = labels[gi];
      rmax[m][q] = -BIGF;
      smax[m][q] = -BIGF;
    }

  f32x4 acc[2][8];
  #pragma unroll
  for (int m = 0; m < 2; ++m)
    #pragma unroll
    for (int n = 0; n < 8; ++n) acc[m][n] = (f32x4){0.f, 0.f, 0.f, 0.f};

  int p = 0;
  for (int jt = 0; jt < TPB; ++jt) {
    #pragma unroll
    for (int kq = 0; kq < 4; ++kq) {
      int np2 = p + 2;
      if (np2 < NPH) stage(np2 >> 2, np2 & 3, np2 & 3);
      if (p < NPH - 2)       asm volatile("s_waitcnt vmcnt(4)" ::: "memory");
      else if (p == NPH - 2) asm volatile("s_waitcnt vmcnt(2)" ::: "memory");
      else                   asm volatile("s_waitcnt vmcnt(0)" ::: "memory");
      __builtin_amdgcn_s_barrier();
      __builtin_amdgcn_sched_barrier(0);
      const char* pb = lds + (p & 3) * 8192;
      __builtin_amdgcn_s_setprio(1);
      #pragma unroll
      for (int n = 0; n < 8; ++n) {
        half8 bh = *reinterpret_cast<const half8*>(pb + boff[n]);
        #pragma unroll
        for (int m = 0; m < 2; ++m)
          acc[m][n] = __builtin_amdgcn_mfma_f32_16x16x32_f16(ah[m][kq], bh, acc[m][n], 0, 0, 0);
      }
      __builtin_amdgcn_s_setprio(0);
      if (kq == 3) {
        #pragma unroll
        for (int n = 0; n < 8; ++n) {
          float njv = snorm[jt * 128 + 16 * n + r16];
          int   ljv = slab[jt * 128 + 16 * n + r16];
          #pragma unroll
          for (int m = 0; m < 2; ++m)
            #pragma unroll
            for (int q = 0; q < 4; ++q) {
              float tv = fmaf(2.f, acc[m][n][q], -njv);
              float tm = (li[m][q] != ljv) ? tv : -BIGF;
              rmax[m][q] = fmaxf(rmax[m][q], tm);
              float tl = (tm < c2[m][q]) ? tm : -BIGF;
              smax[m][q] = fmaxf(smax[m][q], tl);
              acc[m][n][q] = 0.f;
            }
        }
      }
      ++p;
    }
  }

  float2* pp = reinterpret_cast<float2*>(rowres);
  #pragma unroll
  for (int m = 0; m < 2; ++m)
    #pragma unroll
    for (int q = 0; q < 4; ++q) {
      float r = rmax[m][q], s = smax[m][q];
      #pragma unroll
      for (int off = 1; off < 16; off <<= 1) {
        r = fmaxf(r, __shfl_xor(r, off));
        s = fmaxf(s, __shfl_xor(s, off));
      }
      if (r16 == 0) {
        int gi = i0 + 32 * w + 16 * m + 4 * kg + q;
        pp[(size_t)gi * SEGS + seg] = make_float2(r, s);
      }
    }
}

// ---------- k_redout: per-row combine + last-block final scalar --------------
__global__ __launch_bounds__(256) void k_redout(
    const float* __restrict__ norms, const float* __restrict__ hp,
    const float* __restrict__ rowres, float* __restrict__ partial,
    uint* __restrict__ counter, float* __restrict__ out) {
  int row = blockIdx.x * 256 + threadIdx.x;
  const float2* pp = reinterpret_cast<const float2*>(rowres) + (size_t)row * SEGS;
  float rmax = -BIGF, smax = -BIGF;
  #pragma unroll
  for (int s = 0; s < SEGS; ++s) {
    float2 v = pp[s];
    rmax = fmaxf(rmax, v.x);
    smax = fmaxf(smax, v.y);
  }
  float ni = norms[row], h = hp[row];
  float c1 = ni - (h + TMARGIN) * (h + TMARGIN);
  bool has_neg = rmax > -1e37f;
  float neg_sq  = fmaxf(ni - rmax, 0.f);
  float semi_sq = (smax > c1) ? fmaxf(ni - smax, 0.f) : neg_sq;
  float total = 0.f, count = 0.f;
  if (h > 0.f && has_neg) {
    total = fmaxf(h - sqrtf(semi_sq) + TMARGIN, 0.f);
    count = 1.f;
  }
  #pragma unroll
  for (int off = 32; off; off >>= 1) {
    total += __shfl_xor(total, off);
    count += __shfl_xor(count, off);
  }
  __shared__ float st[4], sc[4];
  __shared__ uint done_s;
  int w = threadIdx.x >> 6, lane = threadIdx.x & 63;
  if (lane == 0) { st[w] = total; sc[w] = count; }
  __syncthreads();
  if (threadIdx.x == 0) {
    float2* po = reinterpret_cast<float2*>(partial);
    po[blockIdx.x] = make_float2(st[0] + st[1] + st[2] + st[3],
                                 sc[0] + sc[1] + sc[2] + sc[3]);
    __threadfence();                          // release: partial visible
    done_s = atomicAdd(counter, 1u);          // device-scope
  }
  __syncthreads();
  if (done_s == 31) {                         // last block finalizes
    __threadfence();                          // acquire: see all partials
    if (threadIdx.x < 64) {
      const float2* po = reinterpret_cast<const float2*>(partial);
      float T = 0.f, C = 0.f;
      if (lane < 32) { float2 a = po[lane]; T = a.x; C = a.y; }
      #pragma unroll
      for (int off = 32; off; off >>= 1) {
        T += __shfl_xor(T, off);
        C += __shfl_xor(C, off);
      }
      if (lane == 0) out[0] = C > 0.f ? T / C : 0.f;
    }
  }
}

extern "C" void kernel_launch(void* const* d_in, const int* in_sizes, int n_in,
                              void* d_out, int out_size, void* d_ws, size_t ws_size,
                              hipStream_t stream) {
  const float* emb  = (const float*)d_in[0];
  const int* labels = (const int*)d_in[1];
  float* out        = (float*)d_out;

  _Float16* eh  = (_Float16*)d_ws;                     // 2 MB
  float* norms  = (float*)(eh + (size_t)BATCH * DIM);  // 32 KB
  float* hp     = norms + BATCH;                       // 32 KB
  float* rowres = hp + BATCH;                          // 1 MB (8192 x 16 float2)
  float* partial = rowres + (size_t)BATCH * SEGS * 2;  // 256 B
  uint* counter = (uint*)(partial + 64);               // 4 B

  k_preh<<<2048 + NCLS, 256, 0, stream>>>(emb, labels, eh, norms, hp, counter);
  k_main<<<(BATCH / 128) * SEGS, 256, 0, stream>>>(eh, labels, norms, hp, rowres);
  k_redout<<<BATCH / 256, 256, 0, stream>>>(norms, hp, rowres, partial, counter, out);
}